// Round 11
// baseline (102.152 us; speedup 1.0000x reference)
//
#include <hip/hip_runtime.h>
#include <hip/hip_bf16.h>

typedef __bf16 bf16_t;
typedef __bf16 bf16x8 __attribute__((ext_vector_type(8)));
typedef float f32x4 __attribute__((ext_vector_type(4)));

#define B_   8
#define C_   512
#define HW_  1024
#define NPIX 8192

// ---- async global->LDS (16B per lane) ----
typedef __attribute__((address_space(3))) void lds_vp;
typedef const __attribute__((address_space(1))) void gbl_vp;
__device__ __forceinline__ void gload_lds16(const void* g, void* l) {
    __builtin_amdgcn_global_load_lds((gbl_vp*)g, (lds_vp*)l, 16, 0, 0);
}

// Stage a 128x64 bf16 tile into LDS with the conflict-free swizzle:
// LDS byte layout: row*128 + slot*16, slot = kg ^ (row&7)  (kg = k/8).
__device__ __forceinline__ void stage128x64_swz(const bf16_t* __restrict__ g,
                                                bf16_t* lds, int tid) {
    int w64 = tid & ~63;
#pragma unroll
    for (int s = 0; s < 4; ++s) {
        int u = s * 256 + tid;
        int row = u >> 3;
        int kg = (u & 7) ^ (row & 7);
        const bf16_t* src = g + (size_t)row * 512 + kg * 8;
        gload_lds16((const void*)src, (void*)(lds + (size_t)(s * 256 + w64) * 8));
    }
}

// ---- K1: x [B,C,HW] f32 -> xT [B*HW, C] bf16 ; + weight cvt (fused) ----
__global__ void k_transpose(const float* __restrict__ x, bf16_t* __restrict__ xT,
                            const float* __restrict__ Wq, const float* __restrict__ Wk,
                            bf16_t* __restrict__ wq, bf16_t* __restrict__ wk) {
    __shared__ bf16_t tile[64 * 66];
    int p0 = blockIdx.x * 64, c0 = blockIdx.y * 64, b = blockIdx.z;
    int t = threadIdx.x;
    int widx = ((blockIdx.z * 8 + blockIdx.y) * 16 + blockIdx.x) * 256 + t;
    wq[widx] = (bf16_t)Wq[widx];
    wk[widx] = (bf16_t)Wk[widx];
#pragma unroll
    for (int s = 0; s < 16; ++s) {
        int u = s * 256 + t;
        int cr = u >> 6, pc = u & 63;
        tile[cr * 66 + pc] = (bf16_t)x[((size_t)(b * C_ + c0 + cr)) * HW_ + p0 + pc];
    }
    __syncthreads();
#pragma unroll
    for (int s = 0; s < 16; ++s) {
        int u = s * 256 + t;
        int pr = u >> 6, cc = u & 63;
        xT[((size_t)(b * HW_ + p0 + pr)) * C_ + c0 + cc] = tile[cc * 66 + pr];
    }
}

// ---- K2: q/k projection GEMM (128x128 tiles, swizzled LDS) ----
__launch_bounds__(256, 2)
__global__ void k_gemm_qk(const bf16_t* __restrict__ xT,
                          const bf16_t* __restrict__ wq, const bf16_t* __restrict__ wk,
                          const float* __restrict__ bq, const float* __restrict__ bk,
                          bf16_t* __restrict__ qo, bf16_t* __restrict__ ko) {
    __shared__ __align__(16) bf16_t As[128 * 64];
    __shared__ __align__(16) bf16_t Bs[128 * 64];
    int bid = blockIdx.x;
    int mtile = bid >> 3;
    int nt = bid & 7;
    const bf16_t* wsel = (nt < 4) ? wq : wk;
    const float*  bsel = (nt < 4) ? bq : bk;
    bf16_t*       osel = (nt < 4) ? qo : ko;
    int nb = (nt & 3) * 128;
    int i0 = mtile * 128;
    int tid = threadIdx.x;
    int lane = tid & 63, w = tid >> 6;
    int wr = w >> 1, wc = w & 1, lr = lane & 15, lg = lane >> 4;
    int kswz = (lg ^ (lr & 7)) << 4;

    f32x4 acc[4][4];
#pragma unroll
    for (int mi = 0; mi < 4; ++mi)
#pragma unroll
        for (int ni = 0; ni < 4; ++ni)
#pragma unroll
            for (int r = 0; r < 4; ++r) acc[mi][ni][r] = 0.f;

    for (int kt = 0; kt < 8; ++kt) {
        int k0 = kt * 64;
        stage128x64_swz(xT + (size_t)i0 * 512 + k0, As, tid);
        stage128x64_swz(wsel + (size_t)nb * 512 + k0, Bs, tid);
        asm volatile("s_waitcnt vmcnt(0)" ::: "memory");
        __builtin_amdgcn_s_barrier();
#pragma unroll
        for (int kk = 0; kk < 2; ++kk) {
            bf16x8 af[4], bfr[4];
#pragma unroll
            for (int mi = 0; mi < 4; ++mi)
                af[mi] = *(const bf16x8*)((const char*)As +
                    (wr * 64 + mi * 16 + lr) * 128 + (kswz ^ (kk * 64)));
#pragma unroll
            for (int ni = 0; ni < 4; ++ni)
                bfr[ni] = *(const bf16x8*)((const char*)Bs +
                    (wc * 64 + ni * 16 + lr) * 128 + (kswz ^ (kk * 64)));
#pragma unroll
            for (int mi = 0; mi < 4; ++mi)
#pragma unroll
                for (int ni = 0; ni < 4; ++ni)
                    acc[mi][ni] = __builtin_amdgcn_mfma_f32_16x16x32_bf16(
                        af[mi], bfr[ni], acc[mi][ni], 0, 0, 0);
        }
        __builtin_amdgcn_s_barrier();
    }
#pragma unroll
    for (int ni = 0; ni < 4; ++ni) {
        int col = nb + wc * 64 + ni * 16 + lr;
        float bias = bsel[col];
#pragma unroll
        for (int mi = 0; mi < 4; ++mi) {
            int rowb = i0 + wr * 64 + mi * 16 + lg * 4;
#pragma unroll
            for (int r = 0; r < 4; ++r)
                osel[(size_t)(rowb + r) * 512 + col] = (bf16_t)(acc[mi][ni][r] + bias);
        }
    }
}

// ---- K3: score GEMM + per-key-image-half max, 2 blocks/CU ----
// 512 blocks = (q-panel 256 rows) x (key image) x (key half of 512).
// Per block: 2 n-chunks of 256 keys, 8 K-tiles (BK=64) each = 16 K-tiles.
// LDS 64 KiB: 8 single-buffered regions [128 rows][32 k] = 8 KiB each.
// Swizzle (64B rows, 4 slots of 16B): phys slot = kg ^ ((row>>1)&3) ->
// 8 lanes per bank-group (dense, measured 0 conflicts in round 9).
// Rolling ledger (tile T, P1..P4 = (k0,m0)(k0,m1)(k1,m0)(k1,m1)):
//   P1: stage A[*][k1](T)              (WAR: A[k1](T-1) last read P4(T-1))
//   P2: stage B[*][k0](T+1); vmcnt(2)  (forces A[k1](T)+B[k1](T) for P3)
//   P3: stage A[*][k0](T+1)            (WAR: A[k0](T) last read P2)
//   P4: stage B[*][k1](T+1); vmcnt(2)  (forces A[k0]+B[k0](T+1) for P1')
// Gated loads are 2-3 phases old -> gates ~free. Ledger verified R9; the
// R9 failure was the launch_bounds register cap (spill), fixed here.

#define STAGE_A(RH, KH, T)                                                         \
    gload_lds16((const void*)(q + srcA + (RH) * 65536 + ((T) & 7) * 64 +           \
                              (KH) * 32),                                          \
                (void*)(ldsb + ((RH) * 2 + (KH)) * 8192 + ldst16));

#define STAGE_B(RH, KH, T)                                                         \
    gload_lds16((const void*)(kb + srcB + (size_t)((T) >> 3) * 131072 +            \
                              (RH) * 65536 + ((T) & 7) * 64 + (KH) * 32),          \
                (void*)(ldsb + 32768 + ((RH) * 2 + (KH)) * 8192 + ldst16));

#define PHASE(KH, MH, STG, VM)                                                     \
    {                                                                              \
        const char* Ab = ldsb + (wr * 2 + (KH)) * 8192;                            \
        _Pragma("unroll")                                                          \
        for (int mi = 0; mi < 4; ++mi)                                             \
            af[mi] = *(const bf16x8*)(Ab + aoff + (MH) * 4096 + mi * 1024);        \
        if ((MH) == 0) {                                                           \
            const char* Bb = ldsb + 32768 + ((wc >> 1) * 2 + (KH)) * 8192;         \
            _Pragma("unroll")                                                      \
            for (int ni = 0; ni < 4; ++ni)                                         \
                bf[ni] = *(const bf16x8*)(Bb + boff + ni * 1024);                  \
        }                                                                          \
        STG;                                                                       \
        __builtin_amdgcn_s_setprio(1);                                             \
        _Pragma("unroll")                                                          \
        for (int mi = 0; mi < 4; ++mi)                                             \
            _Pragma("unroll")                                                      \
            for (int ni = 0; ni < 4; ++ni)                                         \
                acc[(MH) * 4 + mi][ni] = __builtin_amdgcn_mfma_f32_16x16x32_bf16(  \
                    af[mi], bf[ni], acc[(MH) * 4 + mi][ni], 0, 0, 0);              \
        __builtin_amdgcn_s_setprio(0);                                             \
        VM;                                                                        \
        __builtin_amdgcn_s_barrier();                                              \
    }

__global__ __launch_bounds__(512, 2)
void k_gemm_max8(const bf16_t* __restrict__ q, const bf16_t* __restrict__ kp,
                 float* __restrict__ Mout2) {
    __shared__ __align__(16) bf16_t lds[32768];   // 64 KiB -> 2 blocks/CU
    char* ldsb = (char*)lds;
    int bid = blockIdx.x;            // 512 blocks: img in low 3 bits (XCD-local)
    int img = bid & 7;
    int nhalf = (bid >> 3) & 1;
    int qp = bid >> 4;               // 0..31
    int i0 = qp * 256;
    const bf16_t* kb = kp + (size_t)img * HW_ * C_;
    int tid = threadIdx.x;
    int lane = tid & 63, w = tid >> 6;
    int wr = w >> 2, wc = w & 3;     // 2 x 4 wave grid; wave tile 128x64
    int lr = lane & 15, lg = lane >> 4;
    int kswz = (lg ^ ((lr >> 1) & 3)) << 4;
    int aoff = lr * 64 + kswz;
    int boff = ((wc & 1) * 64 + lr) * 64 + kswz;

    // staging: thread t writes region bytes [t*16, t*16+16): row = t>>2,
    // phys slot = t&3 -> k-group = (t&3) ^ ((t>>3)&3). Inverse-swizzled src.
    int srow = tid >> 2;
    int skg = (tid & 3) ^ ((tid >> 3) & 3);
    size_t srcA = (size_t)(i0 + srow) * 512 + skg * 8;
    size_t srcB = (size_t)(nhalf * 512 + srow) * 512 + skg * 8;
    int ldst16 = (tid & ~63) * 16;   // wave-uniform LDS byte base

    f32x4 acc[8][4];
    bf16x8 af[4], bf[4];
    float rm[8][4];
#pragma unroll
    for (int mi = 0; mi < 8; ++mi)
#pragma unroll
        for (int ni = 0; ni < 4; ++ni)
#pragma unroll
            for (int r = 0; r < 4; ++r) acc[mi][ni][r] = 0.f;
#pragma unroll
    for (int mi = 0; mi < 8; ++mi)
#pragma unroll
        for (int r = 0; r < 4; ++r) rm[mi][r] = -3.4e38f;

    // prologue: B[k0](0), A[k0](0), B[k1](0); gate all but B[k1]
    STAGE_B(0, 0, 0) STAGE_B(1, 0, 0)
    STAGE_A(0, 0, 0) STAGE_A(1, 0, 0)
    STAGE_B(0, 1, 0) STAGE_B(1, 1, 0)
    asm volatile("s_waitcnt vmcnt(2)" ::: "memory");
    __builtin_amdgcn_s_barrier();

    for (int T = 0; T < 16; ++T) {
        bool s = (T < 15);
        int Tn = T + 1;
        PHASE(0, 0, { STAGE_A(0, 1, T) STAGE_A(1, 1, T) }, {})
        PHASE(0, 1, { if (s) { STAGE_B(0, 0, Tn) STAGE_B(1, 0, Tn) } },
              { if (s) { asm volatile("s_waitcnt vmcnt(2)" ::: "memory"); }
                else   { asm volatile("s_waitcnt vmcnt(0)" ::: "memory"); } })
        PHASE(1, 0, { if (s) { STAGE_A(0, 0, Tn) STAGE_A(1, 0, Tn) } }, {})
        PHASE(1, 1, { if (s) { STAGE_B(0, 1, Tn) STAGE_B(1, 1, Tn) } },
              { if (s) { asm volatile("s_waitcnt vmcnt(2)" ::: "memory"); } })
        if ((T & 7) == 7) {   // n-chunk complete: fold acc into rm, reset acc
#pragma unroll
            for (int mi = 0; mi < 8; ++mi)
#pragma unroll
                for (int r = 0; r < 4; ++r) {
                    float v = fmaxf(fmaxf(acc[mi][0][r], acc[mi][1][r]),
                                    fmaxf(acc[mi][2][r], acc[mi][3][r]));
                    rm[mi][r] = fmaxf(rm[mi][r], v);
#pragma unroll
                    for (int ni = 0; ni < 4; ++ni) acc[mi][ni][r] = 0.f;
                }
        }
    }

    // epilogue: reduce across 16 col-lanes, then across the 4 wc waves
#pragma unroll
    for (int mi = 0; mi < 8; ++mi)
#pragma unroll
        for (int r = 0; r < 4; ++r) {
            float v = rm[mi][r];
#pragma unroll
            for (int off = 1; off < 16; off <<= 1) v = fmaxf(v, __shfl_xor(v, off));
            rm[mi][r] = v;
        }
    float* sm = (float*)lds;
    if (lr == 0) {
#pragma unroll
        for (int mi = 0; mi < 8; ++mi)
#pragma unroll
            for (int r = 0; r < 4; ++r)
                sm[wc * 256 + wr * 128 + mi * 16 + lg * 4 + r] = rm[mi][r];
    }
    __syncthreads();
    if (tid < 256) {
        float v = fmaxf(fmaxf(sm[tid], sm[256 + tid]),
                        fmaxf(sm[512 + tid], sm[768 + tid]));
        Mout2[(size_t)(i0 + tid) * 16 + img * 2 + nhalf] = v;
    }
}

// ---- K4: fold key-halves, mean over key images, scale, softmax ----
__global__ void k_softmax(const float* __restrict__ Mout2, float* __restrict__ wsm) {
    int b = blockIdx.x;
    int t = threadIdx.x;
    __shared__ float red[16];
    const float scale = 0.044194173824159216f;  // 1/sqrt(512)
    float s[4];
#pragma unroll
    for (int i = 0; i < 4; ++i) {
        int p = t + i * 256;
        const float* row = &Mout2[(size_t)(b * 1024 + p) * 16];
        float acc = 0.f;
#pragma unroll
        for (int j = 0; j < 8; ++j) acc += fmaxf(row[2 * j], row[2 * j + 1]);
        s[i] = acc * (scale / 8.0f);
    }
    float m = fmaxf(fmaxf(s[0], s[1]), fmaxf(s[2], s[3]));
#pragma unroll
    for (int off = 1; off < 64; off <<= 1) m = fmaxf(m, __shfl_xor(m, off));
    if ((t & 63) == 0) red[t >> 6] = m;
    __syncthreads();
    float m4 = fmaxf(fmaxf(red[0], red[1]), fmaxf(red[2], red[3]));
    float e[4], sum = 0.f;
#pragma unroll
    for (int i = 0; i < 4; ++i) { e[i] = __expf(s[i] - m4); sum += e[i]; }
#pragma unroll
    for (int off = 1; off < 64; off <<= 1) sum += __shfl_xor(sum, off);
    if ((t & 63) == 0) red[8 + (t >> 6)] = sum;
    __syncthreads();
    float tot = red[8] + red[9] + red[10] + red[11];
    float inv = 1.0f / tot;
#pragma unroll
    for (int i = 0; i < 4; ++i) wsm[b * 1024 + t + i * 256] = e[i] * inv;
}

// ---- K5: y[c] = mean_{b,p} x[b,c,p] * w[b,p] ----
__global__ void k_reduce_y(const float* __restrict__ x, const float* __restrict__ wsm,
                           float* __restrict__ y) {
    int c = blockIdx.x;
    int t = threadIdx.x;
    float acc = 0.f;
    for (int b = 0; b < 8; ++b) {
        const float* xb = x + ((size_t)(b * C_ + c)) * HW_;
        const float* wb = wsm + b * HW_;
#pragma unroll
        for (int i = 0; i < 4; ++i) {
            int p = t + i * 256;
            acc += xb[p] * wb[p];
        }
    }
#pragma unroll
    for (int off = 1; off < 64; off <<= 1) acc += __shfl_xor(acc, off);
    __shared__ float red[4];
    if ((t & 63) == 0) red[t >> 6] = acc;
    __syncthreads();
    if (t == 0) y[c] = (red[0] + red[1] + red[2] + red[3]) * (1.0f / 8192.0f);
}

// ---- K6: x_proto[d] = W6[d,:] . y + b6[d] ----
__global__ void k_proto(const float* __restrict__ W6, const float* __restrict__ b6,
                        const float* __restrict__ y, float* __restrict__ proto) {
    int d = blockIdx.x;
    int lane = threadIdx.x;
    float acc = 0.f;
#pragma unroll
    for (int i = 0; i < 8; ++i)
        acc += W6[(size_t)d * C_ + lane + i * 64] * y[lane + i * 64];
#pragma unroll
    for (int off = 1; off < 64; off <<= 1) acc += __shfl_xor(acc, off);
    if (lane == 0) proto[d] = acc + b6[d];
}

// ---- K7: out = x * proto[c] ----
__global__ void k_final(const float* __restrict__ x, const float* __restrict__ proto,
                        float* __restrict__ out) {
    int idx = blockIdx.x * 256 + threadIdx.x;
    float4 v = ((const float4*)x)[idx];
    int c = (idx >> 8) & 511;
    float p = proto[c];
    v.x *= p; v.y *= p; v.z *= p; v.w *= p;
    ((float4*)out)[idx] = v;
}

extern "C" void kernel_launch(void* const* d_in, const int* in_sizes, int n_in,
                              void* d_out, int out_size, void* d_ws, size_t ws_size,
                              hipStream_t stream) {
    const float* x  = (const float*)d_in[0];
    const float* Wq = (const float*)d_in[1];
    const float* bq = (const float*)d_in[2];
    const float* Wk = (const float*)d_in[3];
    const float* bk = (const float*)d_in[4];
    const float* W6 = (const float*)d_in[5];
    const float* b6 = (const float*)d_in[6];
    float* out = (float*)d_out;

    char* ws = (char*)d_ws;
    bf16_t* xT    = (bf16_t*)(ws);                 // 8.4 MB (dead after k_gemm_qk)
    float*  Mout2 = (float*)(ws);                  // 8192*16*4 = 512 KB, aliases xT
    bf16_t* wqb   = (bf16_t*)(ws + 8388608);
    bf16_t* wkb   = (bf16_t*)(ws + 8912896);
    bf16_t* qb    = (bf16_t*)(ws + 9437184);
    bf16_t* kb    = (bf16_t*)(ws + 17825792);
    float*  wsm   = (float*)(ws + 26476544);
    float*  yv    = (float*)(ws + 26509312);
    float*  proto = (float*)(ws + 26511360);

    hipLaunchKernelGGL(k_transpose, dim3(16, 8, 8), dim3(256), 0, stream,
                       x, xT, Wq, Wk, wqb, wkb);
    hipLaunchKernelGGL(k_gemm_qk, dim3(512), dim3(256), 0, stream,
                       xT, wqb, wkb, bq, bk, qb, kb);
    hipLaunchKernelGGL(k_gemm_max8, dim3(512), dim3(512), 0, stream, qb, kb, Mout2);
    hipLaunchKernelGGL(k_softmax, dim3(8), dim3(256), 0, stream, Mout2, wsm);
    hipLaunchKernelGGL(k_reduce_y, dim3(512), dim3(256), 0, stream, x, wsm, yv);
    hipLaunchKernelGGL(k_proto, dim3(512), dim3(64), 0, stream, W6, b6, yv, proto);
    hipLaunchKernelGGL(k_final, dim3(4096), dim3(256), 0, stream, x, proto, out);
}

// Round 12
// 96.087 us; speedup vs baseline: 1.0631x; 1.0631x over previous
//
#include <hip/hip_runtime.h>
#include <hip/hip_bf16.h>

typedef __bf16 bf16_t;
typedef __bf16 bf16x8 __attribute__((ext_vector_type(8)));
typedef float f32x4 __attribute__((ext_vector_type(4)));

#define B_   8
#define C_   512
#define HW_  1024
#define NPIX 8192

// ---- async global->LDS (16B per lane) ----
typedef __attribute__((address_space(3))) void lds_vp;
typedef const __attribute__((address_space(1))) void gbl_vp;
__device__ __forceinline__ void gload_lds16(const void* g, void* l) {
    __builtin_amdgcn_global_load_lds((gbl_vp*)g, (lds_vp*)l, 16, 0, 0);
}

// Stage a 128x64 bf16 tile into LDS with the conflict-free swizzle:
// LDS byte layout: row*128 + slot*16, slot = kg ^ (row&7)  (kg = k/8).
__device__ __forceinline__ void stage128x64_swz(const bf16_t* __restrict__ g,
                                                bf16_t* lds, int tid) {
    int w64 = tid & ~63;
#pragma unroll
    for (int s = 0; s < 4; ++s) {
        int u = s * 256 + tid;
        int row = u >> 3;
        int kg = (u & 7) ^ (row & 7);
        const bf16_t* src = g + (size_t)row * 512 + kg * 8;
        gload_lds16((const void*)src, (void*)(lds + (size_t)(s * 256 + w64) * 8));
    }
}

// ---- K1: x [B,C,HW] f32 -> xT [B*HW, C] bf16 ; + weight cvt (fused) ----
__global__ void k_transpose(const float* __restrict__ x, bf16_t* __restrict__ xT,
                            const float* __restrict__ Wq, const float* __restrict__ Wk,
                            bf16_t* __restrict__ wq, bf16_t* __restrict__ wk) {
    __shared__ bf16_t tile[64 * 66];
    int p0 = blockIdx.x * 64, c0 = blockIdx.y * 64, b = blockIdx.z;
    int t = threadIdx.x;
    int widx = ((blockIdx.z * 8 + blockIdx.y) * 16 + blockIdx.x) * 256 + t;
    wq[widx] = (bf16_t)Wq[widx];
    wk[widx] = (bf16_t)Wk[widx];
#pragma unroll
    for (int s = 0; s < 16; ++s) {
        int u = s * 256 + t;
        int cr = u >> 6, pc = u & 63;
        tile[cr * 66 + pc] = (bf16_t)x[((size_t)(b * C_ + c0 + cr)) * HW_ + p0 + pc];
    }
    __syncthreads();
#pragma unroll
    for (int s = 0; s < 16; ++s) {
        int u = s * 256 + t;
        int pr = u >> 6, cc = u & 63;
        xT[((size_t)(b * HW_ + p0 + pr)) * C_ + c0 + cc] = tile[cc * 66 + pr];
    }
}

// ---- K2: q/k projection GEMM (128x128 tiles, swizzled LDS) ----
__launch_bounds__(256, 2)
__global__ void k_gemm_qk(const bf16_t* __restrict__ xT,
                          const bf16_t* __restrict__ wq, const bf16_t* __restrict__ wk,
                          const float* __restrict__ bq, const float* __restrict__ bk,
                          bf16_t* __restrict__ qo, bf16_t* __restrict__ ko) {
    __shared__ __align__(16) bf16_t As[128 * 64];
    __shared__ __align__(16) bf16_t Bs[128 * 64];
    int bid = blockIdx.x;
    int mtile = bid >> 3;
    int nt = bid & 7;
    const bf16_t* wsel = (nt < 4) ? wq : wk;
    const float*  bsel = (nt < 4) ? bq : bk;
    bf16_t*       osel = (nt < 4) ? qo : ko;
    int nb = (nt & 3) * 128;
    int i0 = mtile * 128;
    int tid = threadIdx.x;
    int lane = tid & 63, w = tid >> 6;
    int wr = w >> 1, wc = w & 1, lr = lane & 15, lg = lane >> 4;
    int kswz = (lg ^ (lr & 7)) << 4;

    f32x4 acc[4][4];
#pragma unroll
    for (int mi = 0; mi < 4; ++mi)
#pragma unroll
        for (int ni = 0; ni < 4; ++ni)
#pragma unroll
            for (int r = 0; r < 4; ++r) acc[mi][ni][r] = 0.f;

    for (int kt = 0; kt < 8; ++kt) {
        int k0 = kt * 64;
        stage128x64_swz(xT + (size_t)i0 * 512 + k0, As, tid);
        stage128x64_swz(wsel + (size_t)nb * 512 + k0, Bs, tid);
        asm volatile("s_waitcnt vmcnt(0)" ::: "memory");
        __builtin_amdgcn_s_barrier();
#pragma unroll
        for (int kk = 0; kk < 2; ++kk) {
            bf16x8 af[4], bfr[4];
#pragma unroll
            for (int mi = 0; mi < 4; ++mi)
                af[mi] = *(const bf16x8*)((const char*)As +
                    (wr * 64 + mi * 16 + lr) * 128 + (kswz ^ (kk * 64)));
#pragma unroll
            for (int ni = 0; ni < 4; ++ni)
                bfr[ni] = *(const bf16x8*)((const char*)Bs +
                    (wc * 64 + ni * 16 + lr) * 128 + (kswz ^ (kk * 64)));
#pragma unroll
            for (int mi = 0; mi < 4; ++mi)
#pragma unroll
                for (int ni = 0; ni < 4; ++ni)
                    acc[mi][ni] = __builtin_amdgcn_mfma_f32_16x16x32_bf16(
                        af[mi], bfr[ni], acc[mi][ni], 0, 0, 0);
        }
        __builtin_amdgcn_s_barrier();
    }
#pragma unroll
    for (int ni = 0; ni < 4; ++ni) {
        int col = nb + wc * 64 + ni * 16 + lr;
        float bias = bsel[col];
#pragma unroll
        for (int mi = 0; mi < 4; ++mi) {
            int rowb = i0 + wr * 64 + mi * 16 + lg * 4;
#pragma unroll
            for (int r = 0; r < 4; ++r)
                osel[(size_t)(rowb + r) * 512 + col] = (bf16_t)(acc[mi][ni][r] + bias);
        }
    }
}

// ---- K3: score GEMM + per-key-image max, fragment-pipelined 8-phase ----
// 256 blocks = (q-panel 256 rows) x (key image). 32 K-tiles (4 n-chunks x 8).
// LDS: 8 regions [128 rows][128 B]; swizzle byte-in-row ^= (row&7)<<4
// (conflict-free, verified SQ_LDS_BANK_CONFLICT==0).
// SOFTWARE PIPELINE: phase p issues ds_reads for phase p+1 into the ALT
// register set; MFMA(p) consumes the set read at p-1 (no same-phase dep).
// sched_barrier(0) between {reads,stage} and the MFMA cluster pins program
// order so reads ISSUE before the MFMA burst -> LDS pipe services all
// waves' reads underneath the 620-cy MFMA window instead of after it.
// Ledger (iter i: ta=2i in d0, tb=2i+1 in d1, tc=2i+2, td=2i+3):
//   reads@ph_j are frags for ph_{j+1}; stages:
//   ph1:A0d1(tb) ph2:A1d1(tb) ph3:GATE vmcnt(0) ph4:B0d0+B1d0(tc)
//   ph5:A0d0(tc) ph6:A1d0(tc) ph7:GATE vmcnt(0) ph8:B0d1+B1d1(td)
// WAR: stage(R) >= last-read-issue(R)+2 phases. RAW: regions staged+gated
// >=1 phase before first read-issue; gates' newest load >=1 phase old.

#define STAGE_A(RH, D, T)                                                          \
    gload_lds16((const void*)(q + srcA + (size_t)((RH) * 128) * 512 +              \
                              ((T) & 7) * 64),                                     \
                (void*)(ldsb + (RH) * 32768 + (D) * 16384 + ldw));                 \
    gload_lds16((const void*)(q + srcA + (size_t)((RH) * 128 + 64) * 512 +         \
                              ((T) & 7) * 64),                                     \
                (void*)(ldsb + (RH) * 32768 + (D) * 16384 + 8192 + ldw));

#define STAGE_B(RH, D, T)                                                          \
    gload_lds16((const void*)(kb + srcB +                                          \
                              (size_t)(((T) >> 3) * 256 + (RH) * 128) * 512 +      \
                              ((T) & 7) * 64),                                     \
                (void*)(ldsb + 65536 + (RH) * 32768 + (D) * 16384 + ldw));         \
    gload_lds16((const void*)(kb + srcB +                                          \
                              (size_t)(((T) >> 3) * 256 + (RH) * 128 + 64) * 512 + \
                              ((T) & 7) * 64),                                     \
                (void*)(ldsb + 65536 + (RH) * 32768 + (D) * 16384 + 8192 + ldw));

// RSET: af set to fill (for next phase) from region (RD,RKH,RMH);
// RBF/RBSET: whether/where to fill bf; CSET/CMH/CBSET: MFMA consumes.
#define PHASE(RSET, RD, RKH, RMH, RBF, RBSET, CSET, CMH, CBSET, STG, VM)           \
    {                                                                              \
        const char* rAb = ldsb + wr * 32768 + (RD) * 16384;                        \
        _Pragma("unroll")                                                          \
        for (int mi = 0; mi < 4; ++mi)                                             \
            af[RSET][mi] = *(const bf16x8*)(rAb + (aswz ^ ((RKH) * 64)) +          \
                                            ((RMH) * 4 + mi) * 2048);              \
        if (RBF) {                                                                 \
            const char* rBb = ldsb + 65536 + (wc >> 1) * 32768 + (RD) * 16384;     \
            _Pragma("unroll")                                                      \
            for (int ni = 0; ni < 4; ++ni)                                         \
                bf[RBSET][ni] = *(const bf16x8*)(rBb + (bswz ^ ((RKH) * 64)) +     \
                                                 ni * 2048);                       \
        }                                                                          \
        STG;                                                                       \
        __builtin_amdgcn_sched_barrier(0);  /* pin reads BEFORE MFMA burst */      \
        __builtin_amdgcn_s_setprio(1);                                             \
        _Pragma("unroll")                                                          \
        for (int mi = 0; mi < 4; ++mi)                                             \
            _Pragma("unroll")                                                      \
            for (int ni = 0; ni < 4; ++ni)                                         \
                acc[(CMH) * 4 + mi][ni] = __builtin_amdgcn_mfma_f32_16x16x32_bf16( \
                    af[CSET][mi], bf[CBSET][ni], acc[(CMH) * 4 + mi][ni], 0, 0, 0);\
        __builtin_amdgcn_s_setprio(0);                                             \
        VM;                                                                        \
        __builtin_amdgcn_s_barrier();                                              \
    }

__global__ __launch_bounds__(512, 2)
void k_gemm_max8(const bf16_t* __restrict__ q, const bf16_t* __restrict__ kp,
                 float* __restrict__ Mout) {
    __shared__ __align__(16) bf16_t lds[65536];   // 128 KiB
    char* ldsb = (char*)lds;
    int bid = blockIdx.x;           // 256 blocks
    int img = bid & 7;              // XCD-local key image
    int qp = bid >> 3;              // 0..31
    int i0 = qp * 256;
    const bf16_t* kb = kp + (size_t)img * HW_ * C_;
    int tid = threadIdx.x;
    int lane = tid & 63, w = tid >> 6;
    int wr = w >> 2, wc = w & 3;    // 2 x 4 wave grid
    int lr = lane & 15, lg = lane >> 4;
    int kswz = (lg ^ (lr & 7)) << 4;
    int aswz = lr * 128 + kswz;
    int bswz = ((wc & 1) * 64 + lr) * 128 + kswz;

    int srow = tid >> 3;
    int sk = (((tid & 7) ^ ((tid >> 3) & 7))) << 3;
    size_t srcA = (size_t)(i0 + srow) * 512 + sk;
    size_t srcB = (size_t)srow * 512 + sk;
    int ldw = (tid >> 6) * 1024;

    f32x4 acc[8][4];
    bf16x8 af[2][4], bf[2][4];
    float rm[8][4];
#pragma unroll
    for (int mi = 0; mi < 8; ++mi)
#pragma unroll
        for (int ni = 0; ni < 4; ++ni)
#pragma unroll
            for (int r = 0; r < 4; ++r) acc[mi][ni][r] = 0.f;
#pragma unroll
    for (int mi = 0; mi < 8; ++mi)
#pragma unroll
        for (int r = 0; r < 4; ++r) rm[mi][r] = -3.4e38f;

    // prologue: stage t0 d0 (4 regions), t1 d1 B-halves (ph8' slot)
    STAGE_B(0, 0, 0) STAGE_B(1, 0, 0) STAGE_A(0, 0, 0) STAGE_A(1, 0, 0)
    STAGE_B(0, 1, 1) STAGE_B(1, 1, 1)
    asm volatile("s_waitcnt vmcnt(4)" ::: "memory");
    __builtin_amdgcn_s_barrier();
    // prologue fragment reads for ph1: af[0] <- (d0,k0,m0), bf[0] <- B(d0,k0)
    {
        const char* rAb = ldsb + wr * 32768;
#pragma unroll
        for (int mi = 0; mi < 4; ++mi)
            af[0][mi] = *(const bf16x8*)(rAb + aswz + mi * 2048);
        const char* rBb = ldsb + 65536 + (wc >> 1) * 32768;
#pragma unroll
        for (int ni = 0; ni < 4; ++ni)
            bf[0][ni] = *(const bf16x8*)(rBb + bswz + ni * 2048);
    }

    for (int i = 0; i < 16; ++i) {
        int tb = 2 * i + 1, tc = 2 * i + 2, td = 2 * i + 3;
        bool s = (i < 15);
        // ph1: MFMA(d0,k0,m0) set0/bf0 ; read af1<-(d0,k0,m1) ; stage A0d1(tb)
        PHASE(1, 0, 0, 1, 0, 0,  0, 0, 0, { STAGE_A(0, 1, tb) }, {})
        // ph2: MFMA m1 set1/bf0 ; read af0<-(d0,k1,m0), bf1<-B(d0,k1) ; stage A1d1(tb)
        PHASE(0, 0, 1, 0, 1, 1,  1, 1, 0, { STAGE_A(1, 1, tb) }, {})
        // ph3: MFMA m0 set0/bf1 ; read af1<-(d0,k1,m1) ; GATE
        PHASE(1, 0, 1, 1, 0, 0,  0, 0, 1, {},
              { asm volatile("s_waitcnt vmcnt(0)" ::: "memory"); })
        // ph4: MFMA m1 set1/bf1 ; read af0<-(d1,k0,m0), bf0<-B(d1,k0) ; stage B0d0+B1d0(tc)
        PHASE(0, 1, 0, 0, 1, 0,  1, 1, 1,
              { if (s) { STAGE_B(0, 0, tc) STAGE_B(1, 0, tc) } }, {})
        // ph5: MFMA m0 set0/bf0 ; read af1<-(d1,k0,m1) ; stage A0d0(tc)
        PHASE(1, 1, 0, 1, 0, 0,  0, 0, 0, { if (s) { STAGE_A(0, 0, tc) } }, {})
        // ph6: MFMA m1 set1/bf0 ; read af0<-(d1,k1,m0), bf1<-B(d1,k1) ; stage A1d0(tc)
        PHASE(0, 1, 1, 0, 1, 1,  1, 1, 0, { if (s) { STAGE_A(1, 0, tc) } }, {})
        // ph7: MFMA m0 set0/bf1 ; read af1<-(d1,k1,m1) ; GATE
        PHASE(1, 1, 1, 1, 0, 0,  0, 0, 1, {},
              { asm volatile("s_waitcnt vmcnt(0)" ::: "memory"); })
        // ph8: MFMA m1 set1/bf1 ; read af0<-(d0,k0,m0), bf0<-B(d0,k0) [next iter] ;
        //      stage B0d1+B1d1(td)
        PHASE(0, 0, 0, 0, 1, 0,  1, 1, 1,
              { if (s) { STAGE_B(0, 1, td) STAGE_B(1, 1, td) } }, {})
        if ((i & 3) == 3) {   // n-chunk complete: fold acc into rm, reset acc
#pragma unroll
            for (int mi = 0; mi < 8; ++mi)
#pragma unroll
                for (int r = 0; r < 4; ++r) {
                    float v = fmaxf(fmaxf(acc[mi][0][r], acc[mi][1][r]),
                                    fmaxf(acc[mi][2][r], acc[mi][3][r]));
                    rm[mi][r] = fmaxf(rm[mi][r], v);
#pragma unroll
                    for (int ni = 0; ni < 4; ++ni) acc[mi][ni][r] = 0.f;
                }
        }
    }

    // epilogue: reduce across 16 col-lanes, then across the 4 wc waves
#pragma unroll
    for (int mi = 0; mi < 8; ++mi)
#pragma unroll
        for (int r = 0; r < 4; ++r) {
            float v = rm[mi][r];
#pragma unroll
            for (int off = 1; off < 16; off <<= 1) v = fmaxf(v, __shfl_xor(v, off));
            rm[mi][r] = v;
        }
    float* sm = (float*)lds;
    if (lr == 0) {
#pragma unroll
        for (int mi = 0; mi < 8; ++mi)
#pragma unroll
            for (int r = 0; r < 4; ++r)
                sm[wc * 256 + wr * 128 + mi * 16 + lg * 4 + r] = rm[mi][r];
    }
    __syncthreads();
    if (tid < 256) {
        float v = fmaxf(fmaxf(sm[tid], sm[256 + tid]),
                        fmaxf(sm[512 + tid], sm[768 + tid]));
        Mout[(size_t)(i0 + tid) * 8 + img] = v;
    }
}

// ---- K4: mean over key images, scale, softmax per query image ----
__global__ void k_softmax(const float* __restrict__ Mout, float* __restrict__ wsm) {
    int b = blockIdx.x;
    int t = threadIdx.x;
    __shared__ float red[16];
    const float scale = 0.044194173824159216f;  // 1/sqrt(512)
    float s[4];
#pragma unroll
    for (int i = 0; i < 4; ++i) {
        int p = t + i * 256;
        const float* row = &Mout[(size_t)(b * 1024 + p) * 8];
        float acc = 0.f;
#pragma unroll
        for (int j = 0; j < 8; ++j) acc += row[j];
        s[i] = acc * (scale / 8.0f);
    }
    float m = fmaxf(fmaxf(s[0], s[1]), fmaxf(s[2], s[3]));
#pragma unroll
    for (int off = 1; off < 64; off <<= 1) m = fmaxf(m, __shfl_xor(m, off));
    if ((t & 63) == 0) red[t >> 6] = m;
    __syncthreads();
    float m4 = fmaxf(fmaxf(red[0], red[1]), fmaxf(red[2], red[3]));
    float e[4], sum = 0.f;
#pragma unroll
    for (int i = 0; i < 4; ++i) { e[i] = __expf(s[i] - m4); sum += e[i]; }
#pragma unroll
    for (int off = 1; off < 64; off <<= 1) sum += __shfl_xor(sum, off);
    if ((t & 63) == 0) red[8 + (t >> 6)] = sum;
    __syncthreads();
    float tot = red[8] + red[9] + red[10] + red[11];
    float inv = 1.0f / tot;
#pragma unroll
    for (int i = 0; i < 4; ++i) wsm[b * 1024 + t + i * 256] = e[i] * inv;
}

// ---- K5: y[c] = mean_{b,p} x[b,c,p] * w[b,p] ----
__global__ void k_reduce_y(const float* __restrict__ x, const float* __restrict__ wsm,
                           float* __restrict__ y) {
    int c = blockIdx.x;
    int t = threadIdx.x;
    float acc = 0.f;
    for (int b = 0; b < 8; ++b) {
        const float* xb = x + ((size_t)(b * C_ + c)) * HW_;
        const float* wb = wsm + b * HW_;
#pragma unroll
        for (int i = 0; i < 4; ++i) {
            int p = t + i * 256;
            acc += xb[p] * wb[p];
        }
    }
#pragma unroll
    for (int off = 1; off < 64; off <<= 1) acc += __shfl_xor(acc, off);
    __shared__ float red[4];
    if ((t & 63) == 0) red[t >> 6] = acc;
    __syncthreads();
    if (t == 0) y[c] = (red[0] + red[1] + red[2] + red[3]) * (1.0f / 8192.0f);
}

// ---- K6: x_proto[d] = W6[d,:] . y + b6[d] ----
__global__ void k_proto(const float* __restrict__ W6, const float* __restrict__ b6,
                        const float* __restrict__ y, float* __restrict__ proto) {
    int d = blockIdx.x;
    int lane = threadIdx.x;
    float acc = 0.f;
#pragma unroll
    for (int i = 0; i < 8; ++i)
        acc += W6[(size_t)d * C_ + lane + i * 64] * y[lane + i * 64];
#pragma unroll
    for (int off = 1; off < 64; off <<= 1) acc += __shfl_xor(acc, off);
    if (lane == 0) proto[d] = acc + b6[d];
}

// ---- K7: out = x * proto[c] ----
__global__ void k_final(const float* __restrict__ x, const float* __restrict__ proto,
                        float* __restrict__ out) {
    int idx = blockIdx.x * 256 + threadIdx.x;
    float4 v = ((const float4*)x)[idx];
    int c = (idx >> 8) & 511;
    float p = proto[c];
    v.x *= p; v.y *= p; v.z *= p; v.w *= p;
    ((float4*)out)[idx] = v;
}

extern "C" void kernel_launch(void* const* d_in, const int* in_sizes, int n_in,
                              void* d_out, int out_size, void* d_ws, size_t ws_size,
                              hipStream_t stream) {
    const float* x  = (const float*)d_in[0];
    const float* Wq = (const float*)d_in[1];
    const float* bq = (const float*)d_in[2];
    const float* Wk = (const float*)d_in[3];
    const float* bk = (const float*)d_in[4];
    const float* W6 = (const float*)d_in[5];
    const float* b6 = (const float*)d_in[6];
    float* out = (float*)d_out;

    char* ws = (char*)d_ws;
    bf16_t* xT    = (bf16_t*)(ws);                 // 8.4 MB (dead after k_gemm_qk)
    float*  Mout  = (float*)(ws);                  // 8192*8*4 = 256 KB, aliases xT
    bf16_t* wqb   = (bf16_t*)(ws + 8388608);
    bf16_t* wkb   = (bf16_t*)(ws + 8912896);
    bf16_t* qb    = (bf16_t*)(ws + 9437184);
    bf16_t* kb    = (bf16_t*)(ws + 17825792);
    float*  wsm   = (float*)(ws + 26476544);
    float*  yv    = (float*)(ws + 26509312);
    float*  proto = (float*)(ws + 26511360);

    hipLaunchKernelGGL(k_transpose, dim3(16, 8, 8), dim3(256), 0, stream,
                       x, xT, Wq, Wk, wqb, wkb);
    hipLaunchKernelGGL(k_gemm_qk, dim3(512), dim3(256), 0, stream,
                       xT, wqb, wkb, bq, bk, qb, kb);
    hipLaunchKernelGGL(k_gemm_max8, dim3(256), dim3(512), 0, stream, qb, kb, Mout);
    hipLaunchKernelGGL(k_softmax, dim3(8), dim3(256), 0, stream, Mout, wsm);
    hipLaunchKernelGGL(k_reduce_y, dim3(512), dim3(256), 0, stream, x, wsm, yv);
    hipLaunchKernelGGL(k_proto, dim3(512), dim3(64), 0, stream, W6, b6, yv, proto);
    hipLaunchKernelGGL(k_final, dim3(4096), dim3(256), 0, stream, x, proto, out);
}